// Round 2
// baseline (39.189 us; speedup 1.0000x reference)
//
#include <hip/hip_runtime.h>

// Tropical (max-times) matmul: out[i,k] = max_j sigmoid(A[j,k]) * x[i,j]
// x: [2048, 256] f32   A: [256, 512] f32   out: [2048, 512] f32
//
// Round 2 design: NO LDS, NO barriers.
//  - Pre-kernel writes W = sigmoid(A) to d_ws once (removes redundant
//    transcendentals from the hot loop).
//  - Main kernel: one wave owns 8 i-rows x 64 k-cols (lane = one k).
//    x[i,j] is wave-uniform -> scalar (s_load) operands on the SMEM pipe.
//    W[j,k] -> coalesced global_load_dword (256B/wave, L2-hot), register
//    double-buffered in 32-j chunks.
//  - Inner loop is pure v_mul_f32 + v_max3_f32: VALU floor ~12.3k cyc/CU.
//  - 2048 waves total = 8 waves/CU (2 per SIMD) for latency hiding.

constexpr int BATCH = 2048;
constexpr int JD    = 256;
constexpr int KD    = 512;

constexpr int TI = 8;    // i-rows per wave
constexpr int JC = 32;   // j-chunk held in registers

__device__ __forceinline__ float sigmoidf_fast(float a) {
    return 1.0f / (1.0f + __expf(-a));
}

__global__ __launch_bounds__(256) void sigmoid_pre(const float* __restrict__ A,
                                                   float* __restrict__ W) {
    const int idx = (blockIdx.x * 256 + threadIdx.x) * 4;
    float4 a = *(const float4*)(A + idx);
    float4 w;
    w.x = sigmoidf_fast(a.x);
    w.y = sigmoidf_fast(a.y);
    w.z = sigmoidf_fast(a.z);
    w.w = sigmoidf_fast(a.w);
    *(float4*)(W + idx) = w;
}

__global__ __launch_bounds__(256) void tropical_mm_kernel(
        const float* __restrict__ x,
        const float* __restrict__ W,
        float* __restrict__ out) {
    // wave-uniform wave id (readfirstlane => SGPR, makes x addresses
    // provably uniform so they compile to s_load)
    const int wslot = __builtin_amdgcn_readfirstlane((int)(threadIdx.x >> 6));
    const int wid   = (int)blockIdx.x * 4 + wslot;          // 0..2047
    const int lane  = (int)(threadIdx.x & 63);

    const int i0 = (wid >> 3) * TI;                         // 256 i-groups of 8
    const int k  = ((wid & 7) << 6) + lane;                 // 8 k-groups of 64

    const float* Wk = W + k;

    float acc[TI];
    #pragma unroll
    for (int i = 0; i < TI; ++i) acc[i] = -__builtin_inff();

    float wa[JC], wb[JC];

    auto loadw = [&](float (&w)[JC], int jc) {
        const float* p = Wk + jc * KD;
        #pragma unroll
        for (int j = 0; j < JC; ++j) w[j] = p[j * KD];
    };

    auto compute = [&](const float (&w)[JC], int jc) {
        #pragma unroll
        for (int i = 0; i < TI; ++i) {
            // uniform address -> scalar loads (SMEM pipe)
            const float4* xr = (const float4*)(x + (i0 + i) * JD + jc);
            #pragma unroll
            for (int q = 0; q < JC / 4; ++q) {
                const float4 xv = xr[q];
                // fmaxf(fmaxf(p0,p1),acc) -> v_max3_f32
                acc[i] = fmaxf(fmaxf(xv.x * w[4 * q + 0],
                                     xv.y * w[4 * q + 1]), acc[i]);
                acc[i] = fmaxf(fmaxf(xv.z * w[4 * q + 2],
                                     xv.w * w[4 * q + 3]), acc[i]);
            }
        }
    };

    loadw(wa, 0);
    for (int c = 0; c < JD / JC; c += 2) {
        const int jc0 = c * JC;
        const int jc1 = jc0 + JC;
        const int jc2 = jc0 + 2 * JC;
        if (jc1 < JD) loadw(wb, jc1);
        compute(wa, jc0);
        if (jc2 < JD) loadw(wa, jc2);
        if (jc1 < JD) compute(wb, jc1);
    }

    #pragma unroll
    for (int i = 0; i < TI; ++i) out[(i0 + i) * KD + k] = acc[i];
}

extern "C" void kernel_launch(void* const* d_in, const int* in_sizes, int n_in,
                              void* d_out, int out_size, void* d_ws, size_t ws_size,
                              hipStream_t stream) {
    const float* x = (const float*)d_in[0];
    const float* A = (const float*)d_in[1];
    float* out = (float*)d_out;
    float* W   = (float*)d_ws;   // 256*512*4 = 512 KB scratch

    // W = sigmoid(A): 131072 floats / (256 thr * 4) = 128 blocks
    hipLaunchKernelGGL(sigmoid_pre, dim3(128), dim3(256), 0, stream, A, W);

    // 2048 waves = 512 blocks * 4 waves; 8 waves/CU
    hipLaunchKernelGGL(tropical_mm_kernel, dim3(512), dim3(256), 0, stream,
                       x, W, out);
}

// Round 3
// 33.173 us; speedup vs baseline: 1.1814x; 1.1814x over previous
//
#include <hip/hip_runtime.h>

// Tropical (max-times) matmul: out[i,k] = max_j sigmoid(A[j,k]) * x[i,j]
// x: [2048, 256] f32   A: [256, 512] f32   out: [2048, 512] f32
//
// Round 3: lane->k mapping, scalar x operands (s_load_dwordx4, SMEM pipe),
// coalesced per-lane W loads, JC=4 double-buffered register pipeline.
// Key fix vs R2: scalar working set is 2*8 float4 = 64 SGPRs (fits the
// ~102-SGPR budget); all arrays statically indexed (no scratch).
// Inner loop: v_mul_f32 (SGPR x, VGPR w) + v_max3_f32. VALU floor ~5.1us.

constexpr int JD = 256;
constexpr int KD = 512;
constexpr int TI = 8;    // i-rows per wave
constexpr int JC = 4;    // j per chunk

__device__ __forceinline__ float sigmoidf_fast(float a) {
    return 1.0f / (1.0f + __expf(-a));
}

__global__ __launch_bounds__(256) void sigmoid_pre(const float* __restrict__ A,
                                                   float* __restrict__ W) {
    const int idx = (blockIdx.x * 256 + threadIdx.x) * 4;
    float4 a = *(const float4*)(A + idx);
    float4 w;
    w.x = sigmoidf_fast(a.x);
    w.y = sigmoidf_fast(a.y);
    w.z = sigmoidf_fast(a.z);
    w.w = sigmoidf_fast(a.w);
    *(float4*)(W + idx) = w;
}

__global__ __launch_bounds__(256) void tropical_mm_kernel(
        const float* __restrict__ x,
        const float* __restrict__ W,
        float* __restrict__ out) {
    const int lane = (int)(threadIdx.x & 63);
    const int wv   = (int)(threadIdx.x >> 6);     // 4 waves -> 4 k-groups
    const int ig   = (int)blockIdx.x >> 1;        // 256 i-groups
    const int kh   = (int)blockIdx.x & 1;         // k half
    const int i0   = ig * TI;
    const int k    = (kh * 4 + wv) * 64 + lane;   // per-lane k column

    float acc[TI];
    #pragma unroll
    for (int i = 0; i < TI; ++i) acc[i] = -__builtin_inff();

    float4 xA[TI], xB[TI];
    float  wA[JC], wB[JC];

    const float* xr = x + i0 * JD;     // uniform base

    // prologue: chunk 0
    #pragma unroll
    for (int i = 0; i < TI; ++i)
        xA[i] = *(const float4*)(xr + i * JD + 0);
    {
        const float* Wc = W + 0 * KD;  // uniform base; + per-lane k
        #pragma unroll
        for (int j = 0; j < JC; ++j) wA[j] = Wc[j * KD + k];
    }

    #pragma unroll 1
    for (int c = 0; c < JD / JC; c += 2) {
        const int j1 = (c + 1) * JC;
        const int j2 = (c + 2) * JC;

        // prefetch chunk c+1 -> B
        if (j1 < JD) {
            #pragma unroll
            for (int i = 0; i < TI; ++i)
                xB[i] = *(const float4*)(xr + i * JD + j1);
            const float* Wc = W + j1 * KD;
            #pragma unroll
            for (int j = 0; j < JC; ++j) wB[j] = Wc[j * KD + k];
        }

        // compute chunk c (A)
        #pragma unroll
        for (int i = 0; i < TI; ++i) {
            acc[i] = fmaxf(fmaxf(xA[i].x * wA[0], xA[i].y * wA[1]), acc[i]);
            acc[i] = fmaxf(fmaxf(xA[i].z * wA[2], xA[i].w * wA[3]), acc[i]);
        }

        // prefetch chunk c+2 -> A
        if (j2 < JD) {
            #pragma unroll
            for (int i = 0; i < TI; ++i)
                xA[i] = *(const float4*)(xr + i * JD + j2);
            const float* Wc = W + j2 * KD;
            #pragma unroll
            for (int j = 0; j < JC; ++j) wA[j] = Wc[j * KD + k];
        }

        // compute chunk c+1 (B)
        if (j1 < JD) {
            #pragma unroll
            for (int i = 0; i < TI; ++i) {
                acc[i] = fmaxf(fmaxf(xB[i].x * wB[0], xB[i].y * wB[1]), acc[i]);
                acc[i] = fmaxf(fmaxf(xB[i].z * wB[2], xB[i].w * wB[3]), acc[i]);
            }
        }
    }

    #pragma unroll
    for (int i = 0; i < TI; ++i) out[(i0 + i) * KD + k] = acc[i];
}

extern "C" void kernel_launch(void* const* d_in, const int* in_sizes, int n_in,
                              void* d_out, int out_size, void* d_ws, size_t ws_size,
                              hipStream_t stream) {
    const float* x = (const float*)d_in[0];
    const float* A = (const float*)d_in[1];
    float* out = (float*)d_out;
    float* W   = (float*)d_ws;   // 512 KB scratch (proven available in R2)

    hipLaunchKernelGGL(sigmoid_pre, dim3(128), dim3(256), 0, stream, A, W);

    // 512 blocks: (i-group 0..255) x (k-half 0..1); 4 waves/block = 4 k-groups
    hipLaunchKernelGGL(tropical_mm_kernel, dim3(512), dim3(256), 0, stream,
                       x, W, out);
}

// Round 4
// 30.049 us; speedup vs baseline: 1.3042x; 1.1040x over previous
//
#include <hip/hip_runtime.h>

// Tropical (max-times) matmul: out[i,k] = max_j sigmoid(A[j,k]) * x[i,j]
// x: [2048, 256] f32   A: [256, 512] f32   out: [2048, 512] f32
//
// Round 4: latency-tolerance fixes on the scalar-x design.
//  - TI=4 rows/wave, 4096 waves (1024 blocks) -> 4 waves/SIMD (2x R3 TLP).
//  - All 4 waves of a block share ONE k-group (64 k) -> identical W streams
//    -> L1-served; x differs per wave (4KB slabs, scalar-cache-hot).
//  - JC=8 double-buffered: x = 2 x (4 rows x 2 s_load_dwordx4) = 64 SGPRs
//    (fits the ~102 budget, unlike R2), W = 2 x 8 VGPRs.
//  - Inner loop: v_mul_f32 (SGPR x operand) + v_max3_f32.
//    VALU floor: 1536 instr/wave x 2cyc x 4 waves/SIMD = 12.3k cyc ~ 5.1us.

constexpr int JD = 256;
constexpr int KD = 512;
constexpr int TI = 4;    // i-rows per wave
constexpr int JC = 8;    // j per chunk

__device__ __forceinline__ float sigmoidf_fast(float a) {
    return 1.0f / (1.0f + __expf(-a));
}

__global__ __launch_bounds__(256) void sigmoid_pre(const float* __restrict__ A,
                                                   float* __restrict__ W) {
    const int idx = (blockIdx.x * 256 + threadIdx.x) * 4;
    float4 a = *(const float4*)(A + idx);
    float4 w;
    w.x = sigmoidf_fast(a.x);
    w.y = sigmoidf_fast(a.y);
    w.z = sigmoidf_fast(a.z);
    w.w = sigmoidf_fast(a.w);
    *(float4*)(W + idx) = w;
}

__global__ __launch_bounds__(256) void tropical_mm_kernel(
        const float* __restrict__ x,
        const float* __restrict__ W,
        float* __restrict__ out) {
    const int lane = (int)(threadIdx.x & 63);
    // provably-uniform wave slot (readfirstlane -> SGPR) so x addrs scalarize
    const int wv   = __builtin_amdgcn_readfirstlane((int)(threadIdx.x >> 6));
    const int kg   = (int)blockIdx.x & 7;    // 8 k-groups of 64 (shared by block)
    const int ib   = (int)blockIdx.x >> 3;   // 128 i-blocks of 16 rows
    const int i0   = ib * 16 + wv * TI;      // this wave's 4 rows
    const int k    = kg * 64 + lane;         // per-lane k column

    float acc[TI];
    #pragma unroll
    for (int i = 0; i < TI; ++i) acc[i] = -__builtin_inff();

    float4 xA[TI][2], xB[TI][2];   // SGPR-resident (uniform addresses)
    float  wA[JC], wB[JC];         // VGPR-resident (per-lane k)

    const float* xr = x + i0 * JD;   // uniform base
    const float* Wk = W + k;         // per-lane base

    // prologue: chunk 0 -> A
    #pragma unroll
    for (int i = 0; i < TI; ++i) {
        xA[i][0] = *(const float4*)(xr + i * JD + 0);
        xA[i][1] = *(const float4*)(xr + i * JD + 4);
    }
    #pragma unroll
    for (int j = 0; j < JC; ++j) wA[j] = Wk[j * KD];

    #pragma unroll 1
    for (int c = 0; c < JD / JC; c += 2) {
        const int j1 = (c + 1) * JC;
        const int j2 = (c + 2) * JC;

        // prefetch chunk c+1 -> B (j1 <= 248 always)
        #pragma unroll
        for (int j = 0; j < JC; ++j) wB[j] = Wk[(j1 + j) * KD];
        #pragma unroll
        for (int i = 0; i < TI; ++i) {
            xB[i][0] = *(const float4*)(xr + i * JD + j1);
            xB[i][1] = *(const float4*)(xr + i * JD + j1 + 4);
        }

        // compute chunk c (A)
        #pragma unroll
        for (int i = 0; i < TI; ++i) {
            #pragma unroll
            for (int q = 0; q < 2; ++q) {
                const float4 xv = xA[i][q];
                acc[i] = fmaxf(fmaxf(xv.x * wA[4 * q + 0],
                                     xv.y * wA[4 * q + 1]), acc[i]);
                acc[i] = fmaxf(fmaxf(xv.z * wA[4 * q + 2],
                                     xv.w * wA[4 * q + 3]), acc[i]);
            }
        }

        // prefetch chunk c+2 -> A
        if (j2 < JD) {
            #pragma unroll
            for (int j = 0; j < JC; ++j) wA[j] = Wk[(j2 + j) * KD];
            #pragma unroll
            for (int i = 0; i < TI; ++i) {
                xA[i][0] = *(const float4*)(xr + i * JD + j2);
                xA[i][1] = *(const float4*)(xr + i * JD + j2 + 4);
            }
        }

        // compute chunk c+1 (B)
        #pragma unroll
        for (int i = 0; i < TI; ++i) {
            #pragma unroll
            for (int q = 0; q < 2; ++q) {
                const float4 xv = xB[i][q];
                acc[i] = fmaxf(fmaxf(xv.x * wB[4 * q + 0],
                                     xv.y * wB[4 * q + 1]), acc[i]);
                acc[i] = fmaxf(fmaxf(xv.z * wB[4 * q + 2],
                                     xv.w * wB[4 * q + 3]), acc[i]);
            }
        }
    }

    #pragma unroll
    for (int i = 0; i < TI; ++i) out[(i0 + i) * KD + k] = acc[i];
}

extern "C" void kernel_launch(void* const* d_in, const int* in_sizes, int n_in,
                              void* d_out, int out_size, void* d_ws, size_t ws_size,
                              hipStream_t stream) {
    const float* x = (const float*)d_in[0];
    const float* A = (const float*)d_in[1];
    float* out = (float*)d_out;
    float* W   = (float*)d_ws;   // 512 KB scratch

    hipLaunchKernelGGL(sigmoid_pre, dim3(128), dim3(256), 0, stream, A, W);

    // 1024 blocks: (i-block 0..127) x (k-group 0..7); 4 waves/block = 4 i-rows each
    hipLaunchKernelGGL(tropical_mm_kernel, dim3(1024), dim3(256), 0, stream,
                       x, W, out);
}

// Round 6
// 23.566 us; speedup vs baseline: 1.6630x; 1.2751x over previous
//
#include <hip/hip_runtime.h>

// Tropical (max-times) matmul: out[i,k] = max_j sigmoid(A[j,k]) * x[i,j]
// x: [2048, 256] f32   A: [256, 512] f32   out: [2048, 512] f32
//
// Round 6 = Round 5 design with clang-native packed fp16 (the HIP __hmax2
// API is missing in this ROCm's headers).
//  - Pre-kernel: Wp[p][k] = (sig(A[2p][k]), sig(A[2p+1][k])) as 2x_Float16.
//  - Main: block = 16 i-rows x 64 k (4 waves x 4 rows, lane = k).
//    x slab (16x256 -> fp16 pairs, 8KB) staged in LDS once; read via
//    uniform-address ds_read_b128 broadcasts (no SMEM pipe, no conflicts).
//    W pairs: per-lane coalesced global_load_dword, reused over 4 rows.
//    Inner loop: v_pk_mul_f16 + v_pk_max_f16 (2 j per instruction).

constexpr int JD = 256;
constexpr int KD = 512;
constexpr int TI = 4;            // rows per wave
constexpr int ROWS = 16;         // rows per block
constexpr int NCH = 16;          // 16 chunks of 16 j (8 pairs)

typedef _Float16 h1;
typedef __attribute__((ext_vector_type(2))) _Float16 h2v;   // v_pk_* ops
typedef __attribute__((ext_vector_type(4))) float f4;

__device__ __forceinline__ float sigmoidf_fast(float a) {
    return 1.0f / (1.0f + __expf(-a));
}

// Wp[p][k], p = j/2: pair (j=2p, j=2p+1). [128][512] h2v = 256 KB.
__global__ __launch_bounds__(256) void wpack(const float* __restrict__ A,
                                             h2v* __restrict__ Wp) {
    const int t  = blockIdx.x * 256 + threadIdx.x;   // 0..16383
    const int p  = t >> 7;                           // 0..127
    const int kq = (t & 127) << 2;                   // 0,4,..,508
    const f4 a0 = *(const f4*)&A[(2 * p) * KD + kq];
    const f4 a1 = *(const f4*)&A[(2 * p + 1) * KD + kq];
    union { f4 v; h2v h[4]; } u;
    #pragma unroll
    for (int q = 0; q < 4; ++q)
        u.h[q] = h2v{(h1)sigmoidf_fast(a0[q]), (h1)sigmoidf_fast(a1[q])};
    *(f4*)&Wp[p * KD + kq] = u.v;
}

__global__ __launch_bounds__(256, 4) void tropical_mm_kernel(
        const float* __restrict__ x,
        const h2v* __restrict__ Wp,
        float* __restrict__ out) {
    __shared__ h2v xl[ROWS][JD / 2];    // 16 x 128 pairs = 8 KB

    const int t    = (int)threadIdx.x;
    const int lane = t & 63;
    const int wv   = __builtin_amdgcn_readfirstlane(t >> 6);  // 0..3
    const int bk   = (int)blockIdx.x & 7;     // k-group
    const int bi   = (int)blockIdx.x >> 3;    // i-block (0..127)
    const int i0   = bi * ROWS;
    const int k    = bk * 64 + lane;          // per-lane k column

    // ---- stage x slab -> LDS as fp16 pairs (x[j],x[j+1]) ----
    {
        const int srow = t >> 4;              // 0..15
        const int scf  = (t & 15) * 16;       // float col 0,16,..,240
        const float* xs = x + (i0 + srow) * JD + scf;
        f4 f0 = ((const f4*)xs)[0];
        f4 f1 = ((const f4*)xs)[1];
        f4 f2 = ((const f4*)xs)[2];
        f4 f3 = ((const f4*)xs)[3];
        union { f4 v; h2v h[4]; } u0, u1;
        u0.h[0] = h2v{(h1)f0.x, (h1)f0.y};
        u0.h[1] = h2v{(h1)f0.z, (h1)f0.w};
        u0.h[2] = h2v{(h1)f1.x, (h1)f1.y};
        u0.h[3] = h2v{(h1)f1.z, (h1)f1.w};
        u1.h[0] = h2v{(h1)f2.x, (h1)f2.y};
        u1.h[1] = h2v{(h1)f2.z, (h1)f2.w};
        u1.h[2] = h2v{(h1)f3.x, (h1)f3.y};
        u1.h[3] = h2v{(h1)f3.z, (h1)f3.w};
        *(f4*)&xl[srow][(t & 15) * 8]     = u0.v;
        *(f4*)&xl[srow][(t & 15) * 8 + 4] = u1.v;
    }
    __syncthreads();

    const h2v* Wk = Wp + k;          // per-lane base (divergent -> VMEM)
    const int r0 = wv * TI;          // this wave's first row

    h2v acc[TI];
    #pragma unroll
    for (int r = 0; r < TI; ++r)
        acc[r] = h2v{(h1)(-65504.0f), (h1)(-65504.0f)};

    h2v WA[8], WB[8];                // 8 j-pairs per chunk
    f4  XA[TI][2], XB[TI][2];        // per row: 2 x (4 pairs) = 16 j

    auto loadW = [&](h2v (&W)[8], int c) {
        const h2v* p = Wk + (c * 8) * KD;
        #pragma unroll
        for (int q = 0; q < 8; ++q) W[q] = p[q * KD];
    };
    auto loadX = [&](f4 (&X)[TI][2], int c) {
        #pragma unroll
        for (int r = 0; r < TI; ++r) {
            X[r][0] = *(const f4*)&xl[r0 + r][c * 8];
            X[r][1] = *(const f4*)&xl[r0 + r][c * 8 + 4];
        }
    };
    auto compute = [&](const f4 (&X)[TI][2], const h2v (&W)[8]) {
        #pragma unroll
        for (int r = 0; r < TI; ++r) {
            #pragma unroll
            for (int hf = 0; hf < 2; ++hf) {
                union { f4 v; h2v h[4]; } u;
                u.v = X[r][hf];
                #pragma unroll
                for (int q = 0; q < 4; ++q)
                    acc[r] = __builtin_elementwise_max(
                        acc[r], u.h[q] * W[hf * 4 + q]);   // v_pk_mul + v_pk_max
            }
        }
    };

    // ---- software-pipelined main loop ----
    loadW(WA, 0);
    loadX(XA, 0);

    #pragma unroll 1
    for (int c = 0; c < NCH; c += 2) {
        loadW(WB, c + 1);            // NCH even: c+1 always valid
        loadX(XB, c + 1);
        compute(XA, WA);
        if (c + 2 < NCH) {
            loadW(WA, c + 2);
            loadX(XA, c + 2);
        }
        compute(XB, WB);
    }

    // ---- epilogue: fold pair halves, write f32 ----
    #pragma unroll
    for (int r = 0; r < TI; ++r) {
        const float lo = (float)acc[r][0];
        const float hi = (float)acc[r][1];
        out[(i0 + r0 + r) * KD + k] = fmaxf(lo, hi);
    }
}

extern "C" void kernel_launch(void* const* d_in, const int* in_sizes, int n_in,
                              void* d_out, int out_size, void* d_ws, size_t ws_size,
                              hipStream_t stream) {
    const float* x = (const float*)d_in[0];
    const float* A = (const float*)d_in[1];
    float* out = (float*)d_out;
    h2v* Wp = (h2v*)d_ws;   // 256 KB scratch

    hipLaunchKernelGGL(wpack, dim3(64), dim3(256), 0, stream, A, Wp);

    // 1024 blocks: (i-block 0..127) x (k-group 0..7), 4 waves/block
    hipLaunchKernelGGL(tropical_mm_kernel, dim3(1024), dim3(256), 0, stream,
                       x, Wp, out);
}

// Round 7
// 23.192 us; speedup vs baseline: 1.6898x; 1.0161x over previous
//
#include <hip/hip_runtime.h>

// Tropical (max-times) matmul: out[i,k] = max_j sigmoid(A[j,k]) * x[i,j]
// x: [2048, 256] f32   A: [256, 512] f32   out: [2048, 512] f32
//
// Round 7: TK=2 (two k-columns per lane) to halve the LDS broadcast
// return traffic — R6's dominant cost (every broadcast ds_read_b128 still
// writes 64 lanes x 16B of RF). Wave = 4 i x 128 k; block = 16 i x 128 k;
// grid 512 (2 blocks/CU, 8 waves/CU). W loads become dwordx2 (k, k+1),
// output stores dwordx2. Per-CU pipe budget now ~8k cyc each on VALU /
// LDS / TA, overlapping via 8 independent barrier-free waves.

constexpr int JD = 256;
constexpr int KD = 512;
constexpr int TI = 4;            // rows per wave
constexpr int ROWS = 16;         // rows per block
constexpr int NCH = 16;          // chunks of 8 j-pairs (16 j)

typedef _Float16 h1;
typedef __attribute__((ext_vector_type(2))) _Float16 h2v;
typedef __attribute__((ext_vector_type(4))) float f4;
typedef __attribute__((ext_vector_type(2))) float f2;

__device__ __forceinline__ float sigmoidf_fast(float a) {
    return 1.0f / (1.0f + __expf(-a));
}

// Wp[p][k], p = j/2: pair (j=2p, j=2p+1). [128][512] h2v = 256 KB.
__global__ __launch_bounds__(256) void wpack(const float* __restrict__ A,
                                             h2v* __restrict__ Wp) {
    const int t  = blockIdx.x * 256 + threadIdx.x;   // 0..16383
    const int p  = t >> 7;                           // 0..127
    const int kq = (t & 127) << 2;                   // 0,4,..,508
    const f4 a0 = *(const f4*)&A[(2 * p) * KD + kq];
    const f4 a1 = *(const f4*)&A[(2 * p + 1) * KD + kq];
    union { f4 v; h2v h[4]; } u;
    #pragma unroll
    for (int q = 0; q < 4; ++q)
        u.h[q] = h2v{(h1)sigmoidf_fast(a0[q]), (h1)sigmoidf_fast(a1[q])};
    *(f4*)&Wp[p * KD + kq] = u.v;
}

__global__ __launch_bounds__(256) void tropical_mm_kernel(
        const float* __restrict__ x,
        const h2v* __restrict__ Wp,
        float* __restrict__ out) {
    __shared__ h2v xl[ROWS][JD / 2];    // 16 x 128 pairs = 8 KB

    const int t    = (int)threadIdx.x;
    const int lane = t & 63;
    const int wv   = __builtin_amdgcn_readfirstlane(t >> 6);  // 0..3
    const int bk   = (int)blockIdx.x & 3;     // 4 k-supergroups of 128
    const int bi   = (int)blockIdx.x >> 2;    // 128 i-blocks
    const int i0   = bi * ROWS;
    const int k    = bk * 128 + 2 * lane;     // lane owns k, k+1

    // ---- stage x slab -> LDS as fp16 pairs (x[j],x[j+1]) ----
    {
        const int srow = t >> 4;              // 0..15
        const float* xs = x + (i0 + srow) * JD + (t & 15) * 16;
        f4 f0 = ((const f4*)xs)[0];
        f4 f1 = ((const f4*)xs)[1];
        f4 f2_ = ((const f4*)xs)[2];
        f4 f3 = ((const f4*)xs)[3];
        union { f4 v; h2v h[4]; } u0, u1;
        u0.h[0] = h2v{(h1)f0.x, (h1)f0.y};
        u0.h[1] = h2v{(h1)f0.z, (h1)f0.w};
        u0.h[2] = h2v{(h1)f1.x, (h1)f1.y};
        u0.h[3] = h2v{(h1)f1.z, (h1)f1.w};
        u1.h[0] = h2v{(h1)f2_.x, (h1)f2_.y};
        u1.h[1] = h2v{(h1)f2_.z, (h1)f2_.w};
        u1.h[2] = h2v{(h1)f3.x, (h1)f3.y};
        u1.h[3] = h2v{(h1)f3.z, (h1)f3.w};
        *(f4*)&xl[srow][(t & 15) * 8]     = u0.v;
        *(f4*)&xl[srow][(t & 15) * 8 + 4] = u1.v;
    }
    __syncthreads();

    const h2v* Wk = Wp + k;          // per-lane base
    const int r0 = wv * TI;

    h2v acc[TI][2];                  // [row][k-slot]
    #pragma unroll
    for (int r = 0; r < TI; ++r) {
        acc[r][0] = h2v{(h1)(-65504.0f), (h1)(-65504.0f)};
        acc[r][1] = acc[r][0];
    }

    union wpair { f2 v; h2v h[2]; };
    wpair WA[8], WB[8];              // 8 j-pairs x 2 k each (dwordx2 loads)
    f4 XA[TI][2], XB[TI][2];         // per row: 8 pairs = 32B

    auto loadW = [&](wpair (&W)[8], int c) {
        const h2v* p = Wk + (c * 8) * KD;
        #pragma unroll
        for (int q = 0; q < 8; ++q) W[q].v = *(const f2*)&p[q * KD];
    };
    auto loadX = [&](f4 (&X)[TI][2], int c) {
        #pragma unroll
        for (int r = 0; r < TI; ++r) {
            X[r][0] = *(const f4*)&xl[r0 + r][c * 8];
            X[r][1] = *(const f4*)&xl[r0 + r][c * 8 + 4];
        }
    };
    auto compute = [&](const f4 (&X)[TI][2], const wpair (&W)[8]) {
        #pragma unroll
        for (int r = 0; r < TI; ++r) {
            #pragma unroll
            for (int hf = 0; hf < 2; ++hf) {
                union { f4 v; h2v h[4]; } u;
                u.v = X[r][hf];
                #pragma unroll
                for (int q = 0; q < 4; ++q) {
                    const h2v xp = u.h[q];
                    const wpair w = W[hf * 4 + q];
                    acc[r][0] = __builtin_elementwise_max(acc[r][0], xp * w.h[0]);
                    acc[r][1] = __builtin_elementwise_max(acc[r][1], xp * w.h[1]);
                }
            }
        }
    };

    // ---- software-pipelined main loop (no barriers) ----
    loadW(WA, 0);
    loadX(XA, 0);

    #pragma unroll 1
    for (int c = 0; c < NCH; c += 2) {
        loadW(WB, c + 1);            // NCH even: c+1 always valid
        loadX(XB, c + 1);
        compute(XA, WA);
        if (c + 2 < NCH) {
            loadW(WA, c + 2);
            loadX(XA, c + 2);
        }
        compute(XB, WB);
    }

    // ---- epilogue: fold pair halves, write f32 dwordx2 ----
    #pragma unroll
    for (int r = 0; r < TI; ++r) {
        f2 o;
        o.x = fmaxf((float)acc[r][0][0], (float)acc[r][0][1]);
        o.y = fmaxf((float)acc[r][1][0], (float)acc[r][1][1]);
        *(f2*)&out[(i0 + r0 + r) * KD + k] = o;
    }
}

extern "C" void kernel_launch(void* const* d_in, const int* in_sizes, int n_in,
                              void* d_out, int out_size, void* d_ws, size_t ws_size,
                              hipStream_t stream) {
    const float* x = (const float*)d_in[0];
    const float* A = (const float*)d_in[1];
    float* out = (float*)d_out;
    h2v* Wp = (h2v*)d_ws;   // 256 KB scratch

    hipLaunchKernelGGL(wpack, dim3(64), dim3(256), 0, stream, A, Wp);

    // 512 blocks: (i-block 0..127) x (k-super 0..3), 4 waves/block
    hipLaunchKernelGGL(tropical_mm_kernel, dim3(512), dim3(256), 0, stream,
                       x, Wp, out);
}